// Round 5
// baseline (107.196 us; speedup 1.0000x reference)
//
#include <hip/hip_runtime.h>
#include <math.h>

#define EPSF 1e-15f

// ---------------------------------------------------------------------------
// HyperGRU cell, B=H=IN=Cc=256, c=1, fp32.
// _mlr collapses: q[c,b] = tanh(r[b]*|z_c|)*zhat_c, a_unit = zhat_c, so
// px = (-q)(+)x_b lies in span{zhat_c, x_b} -> each _fc = one 256^3 matmul
// Z*X^T + scalar transcendentals. Wh/Uh fc's are dead code in the reference.
//
// R1: VGPR-cap spill -> 262 MB scratch traffic. Fixed.
// R2: harness ws-poison (268 MB fill, ~40 us) is the measurement floor.
// R3: fast transcendentals; fc still latency-bound at 1 wave/SIMD.
// R4: 64x64 split-K=8 mm (2 blocks/CU) FAILED: the _fc scale is broadcast
//     along the COLUMN axis (out[b,j] = (sqrt(sum_c w[j,c]^2)+1) * w[b,j]) —
//     a cross-row dependence that can't live inside a per-row wave.
// R5 (this): K1 unchanged; epilogue split in two:
//     K2 fc_finish: wave-per-row b -> full-K M, fc_elem, W[mat][b][c] + row
//        sums Srow[mat][b] to ws.
//     K3 cell: G[m][c] = (sqrt(Srow[m][c])+1) * W[m][b][c]  (column-indexed
//        scale, coalesced) then the Mobius chain.
//
// ws layout (floats):
//   Mpart [mat][ks][b][c] : (mat*8+ks)*65536
//   nz    [mat][c]        : 2097152
//   na    [mat][c]        : 2098176
//   x2    [src][b]        : 2099200   (src 0=hidden, 1=hyp_x)
//   Srow  [mat][b]        : 2099712
//   W     [mat][b][c]     : 2100736
// ---------------------------------------------------------------------------

#define MPART 0
#define NZOFF 2097152
#define NAOFF 2098176
#define X2OFF 2099200
#define SROFF 2099712
#define WOFF  2100736

// ---- fast transcendentals (v_exp_f32 / v_log_f32 / v_rcp_f32) ----
__device__ __forceinline__ float f_rcp(float x){ return __builtin_amdgcn_rcpf(x); }
__device__ __forceinline__ float f_tanh(float x){
    float e = __expf(2.f * x);
    return 1.f - 2.f * f_rcp(e + 1.f);
}
__device__ __forceinline__ float f_sinh(float x){
    float e = __expf(x);
    return 0.5f * (e - f_rcp(e));
}
__device__ __forceinline__ float f_cosh(float x){
    float e = __expf(x);
    return 0.5f * (e + f_rcp(e));
}
__device__ __forceinline__ float f_asinh(float x){
    float ax = fabsf(x);
    float r = __logf(ax + sqrtf(fmaf(ax, ax, 1.f)));
    return copysignf(r, x);
}
__device__ __forceinline__ float f_artanh(float x){
    return 0.5f * __logf((1.f + x) * f_rcp(1.f - x));
}
__device__ __forceinline__ float f_sigmoid(float x){
    return f_rcp(1.f + __expf(-x));
}

__device__ __forceinline__ float wredsum(float v){
    #pragma unroll
    for (int o = 32; o > 0; o >>= 1) v += __shfl_xor(v, o);
    return v;
}
__device__ __forceinline__ void wredsum3(float& a, float& b, float& c){
    #pragma unroll
    for (int o = 32; o > 0; o >>= 1){
        a += __shfl_xor(a, o);
        b += __shfl_xor(b, o);
        c += __shfl_xor(c, o);
    }
}

// w = sinh(logit) of reference _fc (pre-scale)
__device__ __forceinline__ float fc_elem(float M, float nzc, float nac, float rb, float x2b){
    const float maxn = 1.0f - 4e-3f;
    float d  = M * f_rcp(nzc);
    float tq = f_tanh(rb * nzc);
    if (fabsf(tq) > maxn) tq = copysignf(maxn, tq);
    float A    = fmaf(-2.f*tq, d, 1.f + x2b);
    float den  = fmaxf(fmaf(tq*tq, x2b, fmaf(-2.f*tq, d, 1.f)), EPSF);
    float rden = f_rcp(den);
    float alpha = -tq * A * rden;
    float beta  = (1.f - tq*tq) * rden;
    float dot   = fmaf(beta, d, alpha);
    float pxn2  = fmaxf(alpha*alpha + 2.f*alpha*beta*d + beta*beta*x2b, 0.f);
    float n = fmaxf(sqrtf(pxn2), EPSF);
    if (n > maxn){
        dot *= maxn * f_rcp(n);
        pxn2 = maxn * maxn;
    }
    float lam = 2.f * f_rcp(1.f - pxn2);
    return f_sinh(2.f * nac * f_asinh(dot * lam));
}

// K1: bid<512 -> mm (mat, 64x64 tile, ks of K=32); bid>=512 -> row norms.
__global__ __launch_bounds__(256) void mm_norm_kernel(
    const float* __restrict__ hidden, const float* __restrict__ hyp_x,
    const float* __restrict__ Wz_z, const float* __restrict__ Uz_z,
    const float* __restrict__ Wr_z, const float* __restrict__ Ur_z,
    const float* __restrict__ Wz_r, const float* __restrict__ Uz_r,
    const float* __restrict__ Wr_r, const float* __restrict__ Ur_r,
    float* __restrict__ ws)
{
    __shared__ float smem[4608];     // As[64][36] | Bs[64][36]; Ts[64][65] aliases after barrier
    const int bid = blockIdx.x;
    const int t   = threadIdx.x;

    if (bid < 512){
        const int mat   = bid >> 7;
        const int rest  = bid & 127;
        const int tile  = rest >> 3;
        const int ks    = rest & 7;
        const int cbase = (tile >> 2) * 64;
        const int bbase = (tile & 3) * 64;
        const int k0    = ks * 32;

        const float* Z = (mat==0) ? Wz_z : (mat==1) ? Uz_z : (mat==2) ? Wr_z : Ur_z;
        const float* X = ((mat & 1) == 0) ? hidden : hyp_x;

        float* As = smem;            // [64][36]
        float* Bs = smem + 2304;     // [64][36]

        // stage 64x32 tiles (512 float4 each, 2 per thread), coalesced
        #pragma unroll
        for (int q = 0; q < 2; ++q){
            int slot = q*256 + t;
            int row  = slot >> 3;
            int col  = (slot & 7) * 4;
            *(float4*)&As[row*36 + col] = *(const float4*)(Z + (cbase+row)*256 + k0 + col);
            *(float4*)&Bs[row*36 + col] = *(const float4*)(X + (bbase+row)*256 + k0 + col);
        }
        __syncthreads();

        // 4x4 interleaved micro-tile: rows {tc+16i}, cols {tb+16j}
        const int tc = t >> 4, tb = t & 15;
        float acc[4][4];
        #pragma unroll
        for (int i = 0; i < 4; ++i)
            #pragma unroll
            for (int j = 0; j < 4; ++j) acc[i][j] = 0.f;

        #pragma unroll 2
        for (int kc = 0; kc < 8; ++kc){
            int k = kc * 4;
            float4 a0 = *(const float4*)&As[(tc     )*36 + k];
            float4 a1 = *(const float4*)&As[(tc + 16)*36 + k];
            float4 a2 = *(const float4*)&As[(tc + 32)*36 + k];
            float4 a3 = *(const float4*)&As[(tc + 48)*36 + k];
            float4 b0 = *(const float4*)&Bs[(tb     )*36 + k];
            float4 b1 = *(const float4*)&Bs[(tb + 16)*36 + k];
            float4 b2 = *(const float4*)&Bs[(tb + 32)*36 + k];
            float4 b3 = *(const float4*)&Bs[(tb + 48)*36 + k];
            const float4 av[4] = {a0,a1,a2,a3};
            const float4 bv[4] = {b0,b1,b2,b3};
            #pragma unroll
            for (int i = 0; i < 4; ++i)
                #pragma unroll
                for (int j = 0; j < 4; ++j){
                    acc[i][j] += av[i].x*bv[j].x + av[i].y*bv[j].y
                               + av[i].z*bv[j].z + av[i].w*bv[j].w;
                }
        }
        __syncthreads();             // As/Bs dead; reuse as Ts

        // transpose to [b_local][c_local] in LDS, then coalesced store
        float* Ts = smem;            // [64][65]
        #pragma unroll
        for (int i = 0; i < 4; ++i)
            #pragma unroll
            for (int j = 0; j < 4; ++j)
                Ts[(tb + 16*j)*65 + (tc + 16*i)] = acc[i][j];
        __syncthreads();

        float* Mp = ws + MPART + ((mat*8 + ks) << 16);
        const int bl = t >> 2;
        const int cs = (t & 3) * 4;
        #pragma unroll
        for (int s = 0; s < 4; ++s){
            float4 v;
            v.x = Ts[bl*65 + cs + 16*s + 0];
            v.y = Ts[bl*65 + cs + 16*s + 1];
            v.z = Ts[bl*65 + cs + 16*s + 2];
            v.w = Ts[bl*65 + cs + 16*s + 3];
            *(float4*)(Mp + (bbase + bl)*256 + (cbase + cs + 16*s)) = v;
        }
    } else {
        // row norms: 1536 rows (4 Z mats + hidden + hyp_x), one wave per row
        const int wv   = t >> 6;
        const int lane = t & 63;
        const int g    = (bid - 512)*4 + wv;      // 0..1535
        const int src  = g >> 8;
        const int row  = g & 255;
        const float* sp = (src==0) ? Wz_z : (src==1) ? Uz_z : (src==2) ? Wr_z
                        : (src==3) ? Ur_z : (src==4) ? hidden : hyp_x;
        float4 v = *(const float4*)(sp + row*256 + lane*4);
        float s = v.x*v.x + v.y*v.y + v.z*v.z + v.w*v.w;
        s = wredsum(s);
        if (lane == 0){
            if (src < 4){
                float nz = fmaxf(sqrtf(s), EPSF);
                ws[NZOFF + src*256 + row] = nz;
                const float* rv = (src==0) ? Wz_r : (src==1) ? Uz_r : (src==2) ? Wr_r : Ur_r;
                float ch = f_cosh(rv[row]);
                ws[NAOFF + src*256 + row] = nz * f_rcp(ch*ch);
            } else {
                ws[X2OFF + (src-4)*256 + row] = s;
            }
        }
    }
}

// K2: wave-per-row b. Sum K-partials, fc_elem -> w[b][c], row sum Srow[mat][b].
__global__ __launch_bounds__(256) void fc_finish_kernel(
    const float* __restrict__ Wz_r, const float* __restrict__ Uz_r,
    const float* __restrict__ Wr_r, const float* __restrict__ Ur_r,
    float* __restrict__ ws)
{
    const int b    = blockIdx.x * 4 + (threadIdx.x >> 6);
    const int lane = threadIdx.x & 63;
    const int c4   = lane * 4;

    #pragma unroll
    for (int m = 0; m < 4; ++m){
        const float* Mp = ws + MPART + ((m*8) << 16) + b*256 + c4;
        float4 M = *(const float4*)Mp;
        #pragma unroll
        for (int ks = 1; ks < 8; ++ks){
            float4 p = *(const float4*)(Mp + (ks << 16));
            M.x += p.x; M.y += p.y; M.z += p.z; M.w += p.w;
        }
        float4 nz = *(const float4*)(ws + NZOFF + m*256 + c4);
        float4 na = *(const float4*)(ws + NAOFF + m*256 + c4);
        const float* rv = (m==0) ? Wz_r : (m==1) ? Uz_r : (m==2) ? Wr_r : Ur_r;
        float rb  = rv[b];
        float x2b = ws[X2OFF + (m & 1)*256 + b];    // m0,2->hidden, m1,3->hyp_x
        float4 w;
        w.x = fc_elem(M.x, nz.x, na.x, rb, x2b);
        w.y = fc_elem(M.y, nz.y, na.y, rb, x2b);
        w.z = fc_elem(M.z, nz.z, na.z, rb, x2b);
        w.w = fc_elem(M.w, nz.w, na.w, rb, x2b);
        float S = wredsum(w.x*w.x + w.y*w.y + w.z*w.z + w.w*w.w);
        *(float4*)(ws + WOFF + m*65536 + b*256 + c4) = w;
        if (lane == 0) ws[SROFF + m*256 + b] = S;
    }
}

// wave-per-row Mobius add with projection; returns final norm (>= EPSF)
__device__ __forceinline__ float mobius_add4(const float x[4], const float y[4], float res[4]){
    float x2 = 0.f, y2 = 0.f, xy = 0.f;
    #pragma unroll
    for (int k = 0; k < 4; ++k){ x2 += x[k]*x[k]; y2 += y[k]*y[k]; xy += x[k]*y[k]; }
    wredsum3(x2, y2, xy);
    float cA  = 1.f + 2.f*xy + y2;
    float cB  = 1.f - x2;
    float rden = f_rcp(fmaxf(1.f + 2.f*xy + x2*y2, EPSF));
    float n2  = 0.f;
    #pragma unroll
    for (int k = 0; k < 4; ++k){ res[k] = (cA*x[k] + cB*y[k]) * rden; n2 += res[k]*res[k]; }
    n2 = wredsum(n2);
    float n = fmaxf(sqrtf(n2), EPSF);
    const float maxn = 1.0f - 4e-3f;
    if (n > maxn){
        float s = maxn * f_rcp(n);
        #pragma unroll
        for (int k = 0; k < 4; ++k) res[k] *= s;
        n = maxn;
    }
    return n;
}

// K3: one wave per output row b. G[m] = (sqrt(Srow[m][c])+1) * W[m][b][c]
// (scale is COLUMN-indexed per the reference's scale[None,:] broadcast),
// then the Mobius/logmap/sigmoid/pw-mul chain.
__global__ __launch_bounds__(256) void cell_kernel(
    const float* __restrict__ hidden,
    const float* __restrict__ b_z, const float* __restrict__ b_r, const float* __restrict__ b_h,
    const float* __restrict__ ws, float* __restrict__ out)
{
    const int b    = blockIdx.x * 4 + (threadIdx.x >> 6);
    const int lane = threadIdx.x & 63;
    const int c4   = lane * 4;
    const float maxn = 1.0f - 4e-3f;

    // ---- phase A: G[mat][0..3] ----
    float G[4][4];
    #pragma unroll
    for (int m = 0; m < 4; ++m){
        float4 w  = *(const float4*)(ws + WOFF  + m*65536 + b*256 + c4);
        float4 Sr = *(const float4*)(ws + SROFF + m*256 + c4);   // column-indexed!
        G[m][0] = (sqrtf(Sr.x) + 1.f) * w.x;
        G[m][1] = (sqrtf(Sr.y) + 1.f) * w.y;
        G[m][2] = (sqrtf(Sr.z) + 1.f) * w.z;
        G[m][3] = (sqrtf(Sr.w) + 1.f) * w.w;
    }

    // ---- phase B ----
    float h[4], t1[4], pre[4], zv[4], rv4[4], ht[4], tmp[4], pw[4], mh[4];
    { float4 hv = *(const float4*)(hidden + b*256 + c4);
      h[0]=hv.x; h[1]=hv.y; h[2]=hv.z; h[3]=hv.w; }

    // z gate
    mobius_add4(G[0], G[1], t1);
    { float4 bb = *(const float4*)(b_z + c4); tmp[0]=bb.x; tmp[1]=bb.y; tmp[2]=bb.z; tmp[3]=bb.w; }
    float n  = mobius_add4(t1, tmp, pre);
    float sc = f_artanh(fminf(n, 1.f - 1e-7f)) * f_rcp(n);
    #pragma unroll
    for (int k = 0; k < 4; ++k) zv[k] = f_sigmoid(pre[k]*sc);

    // r gate
    mobius_add4(G[2], G[3], t1);
    { float4 bb = *(const float4*)(b_r + c4); tmp[0]=bb.x; tmp[1]=bb.y; tmp[2]=bb.z; tmp[3]=bb.w; }
    n  = mobius_add4(t1, tmp, pre);
    sc = f_artanh(fminf(n, 1.f - 1e-7f)) * f_rcp(n);
    #pragma unroll
    for (int k = 0; k < 4; ++k) rv4[k] = f_sigmoid(pre[k]*sc);

    // h_tilde = r (+) b_h
    { float4 bb = *(const float4*)(b_h + c4); tmp[0]=bb.x; tmp[1]=bb.y; tmp[2]=bb.z; tmp[3]=bb.w; }
    mobius_add4(rv4, tmp, ht);

    // mh = (-hidden) (+) h_tilde
    #pragma unroll
    for (int k = 0; k < 4; ++k) tmp[k] = -h[k];
    mobius_add4(tmp, ht, mh);

    // pw = mobius_pointwise_mul(mh, z)
    float xn2 = 0.f, wxn2 = 0.f, dum = 0.f;
    #pragma unroll
    for (int k = 0; k < 4; ++k){ tmp[k] = mh[k]*zv[k]; xn2 += zv[k]*zv[k]; wxn2 += tmp[k]*tmp[k]; }
    wredsum3(xn2, wxn2, dum);
    float xn  = fmaxf(sqrtf(xn2),  EPSF);
    float wxn = fmaxf(sqrtf(wxn2), EPSF);
    float th  = f_tanh(wxn * f_rcp(xn) * f_artanh(fminf(xn, 1.f - 1e-7f)));
    float coef = th * f_rcp(wxn);
    if (th > maxn) coef *= maxn * f_rcp(th);
    #pragma unroll
    for (int k = 0; k < 4; ++k) pw[k] = coef * tmp[k];

    // out = hidden (+) pw
    mobius_add4(h, pw, tmp);
    float4 o; o.x = tmp[0]; o.y = tmp[1]; o.z = tmp[2]; o.w = tmp[3];
    *(float4*)(out + b*256 + c4) = o;
}

extern "C" void kernel_launch(void* const* d_in, const int* in_sizes, int n_in,
                              void* d_out, int out_size, void* d_ws, size_t ws_size,
                              hipStream_t stream) {
    (void)in_sizes; (void)n_in; (void)out_size; (void)ws_size;
    const float* hyp_x  = (const float*)d_in[0];
    const float* hidden = (const float*)d_in[1];
    const float* Wz_z   = (const float*)d_in[2];
    const float* Wz_r   = (const float*)d_in[3];
    const float* Uz_z   = (const float*)d_in[4];
    const float* Uz_r   = (const float*)d_in[5];
    const float* Wr_z   = (const float*)d_in[6];
    const float* Wr_r   = (const float*)d_in[7];
    const float* Ur_z   = (const float*)d_in[8];
    const float* Ur_r   = (const float*)d_in[9];
    // d_in[10..13] (Wh_z, Wh_r, Uh_z, Uh_r) are dead in the reference
    const float* b_z    = (const float*)d_in[14];
    const float* b_r    = (const float*)d_in[15];
    const float* b_h    = (const float*)d_in[16];
    float* ws  = (float*)d_ws;
    float* out = (float*)d_out;

    mm_norm_kernel<<<dim3(896), dim3(256), 0, stream>>>(
        hidden, hyp_x, Wz_z, Uz_z, Wr_z, Ur_z, Wz_r, Uz_r, Wr_r, Ur_r, ws);
    fc_finish_kernel<<<dim3(64), dim3(256), 0, stream>>>(
        Wz_r, Uz_r, Wr_r, Ur_r, ws);
    cell_kernel<<<dim3(64), dim3(256), 0, stream>>>(
        hidden, b_z, b_r, b_h, ws, out);
}